// Round 1
// baseline (516.773 us; speedup 1.0000x reference)
//
#include <hip/hip_runtime.h>
#include <cstdint>
#include <cstddef>

// ---------------------------------------------------------------------------
// CrossAttention2D: out = softmax((rope(XqWq^T) rope(XkWk^T)^T)/8) (XvWv^T) Wo^T
// B=4, N=48*48=2304, E=1024, H=16, D=64. bf16 MFMA, fp32 accum.
// R6: (1) PV switched from half-rate mfma_f32_16x16x16_f16 to full-rate
//     16x16x32_f16 via a K-token bit-permutation ([hi q1 q0 c r1 r0] ->
//     [hi c q1 q0 r1 r0] within each 64-token block) applied at gemm_qk's
//     K write; V repacked as 8-token 16B chunks (XOR-swizzled) so the
//     x32 A-fragment is one ds_read_b128. (2) attn + all GEMMs moved to
//     3-buffer LDS pipeline: one raw s_barrier per K-tile, counted
//     s_waitcnt vmcnt(4) (never a full drain in the main loop), 2 tiles
//     prefetch depth. (3) s_setprio(1) around MFMA clusters.
// ---------------------------------------------------------------------------

typedef __bf16 bf16x8 __attribute__((ext_vector_type(8)));
typedef __bf16 bf16x4 __attribute__((ext_vector_type(4)));
typedef _Float16 f16x4 __attribute__((ext_vector_type(4)));
typedef _Float16 f16x8 __attribute__((ext_vector_type(8)));
typedef float f32x4 __attribute__((ext_vector_type(4)));

constexpr int Bc = 4, Hc = 16, Nc = 2304, Ec = 1024, WPc = 48;
constexpr int BNc = Bc * Nc;  // 9216

__device__ __forceinline__ f32x4 mfma16(bf16x8 a, bf16x8 b, f32x4 c) {
  return __builtin_amdgcn_mfma_f32_16x16x32_bf16(a, b, c, 0, 0, 0);
}
__device__ __forceinline__ f32x4 mfmah32(f16x8 a, f16x8 b, f32x4 c) {
  return __builtin_amdgcn_mfma_f32_16x16x32_f16(a, b, c, 0, 0, 0);
}

#define GPTR(p) ((const __attribute__((address_space(1))) void*)(p))
#define LPTR(p) ((__attribute__((address_space(3))) void*)(p))

// --------------------------- fp32 -> bf16 convert ---------------------------
__global__ __launch_bounds__(256) void cvt_bf16(const float* __restrict__ s,
                                                __bf16* __restrict__ d, int n) {
  int i = (blockIdx.x * 256 + threadIdx.x) * 8;
  if (i >= n) return;
  float4 f0 = *(const float4*)(s + i);
  float4 f1 = *(const float4*)(s + i + 4);
  bf16x8 v;
  v[0] = (__bf16)f0.x; v[1] = (__bf16)f0.y; v[2] = (__bf16)f0.z; v[3] = (__bf16)f0.w;
  v[4] = (__bf16)f1.x; v[5] = (__bf16)f1.y; v[6] = (__bf16)f1.z; v[7] = (__bf16)f1.w;
  *(bf16x8*)(d + i) = v;
}

// ---------------- shared GEMM core: 128x128 tile, BK=32, 4 waves ------------
// 3-buffer pipeline: 1 barrier per K-tile, counted vmcnt(4), 2-tile prefetch.

#define GSTAGE(KK, BUF)                                                         \
  {                                                                             \
    _Pragma("unroll") for (int tch = 0; tch < 2; ++tch) {                       \
      const int ch = wave * 2 + tch;                                            \
      const int row = ch * 16 + rowInC;                                         \
      __builtin_amdgcn_global_load_lds(GPTR(Ab + (size_t)row * KD + (KK) + colC), \
                                       LPTR(&As[BUF][ch * 512]), 16, 0, 0);     \
      __builtin_amdgcn_global_load_lds(GPTR(Wb + (size_t)row * KD + (KK) + colC), \
                                       LPTR(&Bs[BUF][ch * 512]), 16, 0, 0);     \
    }                                                                           \
  }

#define GPHASE(KT, BUF, WN, DS)                                                 \
  asm volatile("s_waitcnt vmcnt(" #WN ")" ::: "memory");                        \
  __builtin_amdgcn_s_barrier();                                                 \
  asm volatile("" ::: "memory");                                                \
  if (DS) GSTAGE(((KT) + 2) * 32, ((BUF) + 2) % 3)                              \
  {                                                                             \
    bf16x8 af[4], bfg[4];                                                       \
    _Pragma("unroll") for (int i = 0; i < 4; ++i)                               \
        af[i] = *(const bf16x8*)(&As[BUF][(wm * 64 + i * 16 + l15) * 32 + quad * 8]); \
    _Pragma("unroll") for (int j = 0; j < 4; ++j)                               \
        bfg[j] = *(const bf16x8*)(&Bs[BUF][(wn * 64 + j * 16 + l15) * 32 + quad * 8]); \
    __builtin_amdgcn_s_setprio(1);                                              \
    _Pragma("unroll") for (int i = 0; i < 4; ++i)                               \
      _Pragma("unroll") for (int j = 0; j < 4; ++j)                             \
        acc[i][j] = mfma16(af[i], bfg[j], acc[i][j]);                           \
    __builtin_amdgcn_s_setprio(0);                                              \
  }

#define GEMM_CORE(APTR, WPTR, KDIM)                                             \
  __shared__ __align__(16) __bf16 As[3][128 * 32];                              \
  __shared__ __align__(16) __bf16 Bs[3][128 * 32];                              \
  const int t = threadIdx.x;                                                    \
  const int lane = t & 63, wave = t >> 6;                                       \
  const int wm = wave & 1, wn = wave >> 1;                                      \
  const int quad = lane >> 4, l15 = lane & 15;                                  \
  const int rowInC = lane >> 2, colC = (lane & 3) * 8;                          \
  const int KD = (KDIM);                                                        \
  const __bf16* Ab = (APTR) + (size_t)(tm * 128) * KD;                          \
  const __bf16* Wb = (WPTR) + (size_t)(tn * 128) * KD;                          \
  f32x4 zero = {0.f, 0.f, 0.f, 0.f};                                            \
  f32x4 acc[4][4];                                                              \
  for (int i = 0; i < 4; ++i)                                                   \
    for (int j = 0; j < 4; ++j) acc[i][j] = zero;                               \
  GSTAGE(0, 0)                                                                  \
  GSTAGE(32, 1)                                                                 \
  _Pragma("unroll 1") for (int kt = 0; kt < KD / 32 - 2; kt += 3) {             \
    GPHASE(kt, 0, 4, 1)                                                         \
    GPHASE(kt + 1, 1, 4, 1)                                                     \
    GPHASE(kt + 2, 2, 4, 1)                                                     \
  }                                                                             \
  GPHASE(KD / 32 - 2, 0, 4, 0)                                                  \
  GPHASE(KD / 32 - 1, 1, 0, 0)                                                  \
  const int m0 = tm * 128 + wm * 64;                                            \
  const int nb0 = tn * 128 + wn * 64;

// ---------------- GEMM 1: fused Q+K projection + RoPE + head pack -----------
// Col tiles 0..7 -> Q (natural order); 8..15 -> K. K rows get BOTH the 16B
// d-chunk XOR swizzle (by stored-position low bits) AND the token
// bit-permutation within each 64-block: t64=[hi q1 q0 c r1 r0] is stored at
// position p=[hi c q1 q0 r1 r0], so QK^T's C-regs line up with the k-slots
// (k = quad*8+j) of the 16x16x32 PV B-fragment with zero cross-lane traffic.
__global__ __launch_bounds__(256) void gemm_qk(const __bf16* __restrict__ qkb,
                                               const __bf16* __restrict__ Wqk,
                                               const float* __restrict__ bq,
                                               const float* __restrict__ bk,
                                               __bf16* __restrict__ Qhp,
                                               __bf16* __restrict__ Khp,
                                               float qscale) {
  const int tn = blockIdx.x & 15;   // 16 col tiles over 2048
  const int tm = blockIdx.x >> 4;   // 72 row tiles
  const int proj = tn >> 3;         // 0 = Q, 1 = K (block-uniform)
  const __bf16* Asel = qkb + (size_t)proj * BNc * Ec;
  GEMM_CORE(Asel, Wqk, Ec)

  const int h = (nb0 >> 6) & 15;
  const float scale = proj ? 1.0f : qscale;
  __bf16* O = proj ? Khp : Qhp;
  const float* bb = proj ? bk : bq;
  float bj[4];
#pragma unroll
  for (int j = 0; j < 4; ++j) bj[j] = bb[(nb0 + j * 16 + l15) & 1023];
  const float f = exp2f(-(float)l15 * 0.8304820237218406f);
  const int lo3 = l15 & 7, hi8 = l15 >> 3;
#pragma unroll
  for (int i = 0; i < 4; ++i) {
#pragma unroll
    for (int r = 0; r < 4; ++r) {
      const int m = m0 + i * 16 + quad * 4 + r;
      const int b = m / Nc;
      const int ntok = m - b * Nc;
      const int ph = ntok / WPc, pw = ntok - (ntok / WPc) * WPc;
      float sh, ch, sw, cw;
      __sincosf((float)ph * f, &sh, &ch);
      __sincosf((float)pw * f, &sw, &cw);
      const float x0 = acc[i][0][r] + bj[0];
      const float x1 = acc[i][1][r] + bj[1];
      const float x2 = acc[i][2][r] + bj[2];
      const float x3 = acc[i][3][r] + bj[3];
      int wtok = ntok;
      if (proj) {
        const int t64 = ntok & 63;
        wtok = (ntok & ~63) | (t64 & 35) | ((t64 & 4) << 2) | ((t64 & 24) >> 1);
      }
      __bf16* Op = O + ((size_t)(b * Hc + h) * Nc + wtok) * 64;
      const int n7 = proj ? (wtok & 7) : 0;
      Op[(((0 + hi8) ^ n7) << 3) | lo3] = (__bf16)((x0 * ch - x1 * sh) * scale);
      Op[(((2 + hi8) ^ n7) << 3) | lo3] = (__bf16)((x1 * ch + x0 * sh) * scale);
      Op[(((4 + hi8) ^ n7) << 3) | lo3] = (__bf16)((x2 * cw - x3 * sw) * scale);
      Op[(((6 + hi8) ^ n7) << 3) | lo3] = (__bf16)((x3 * cw + x2 * sw) * scale);
    }
  }
}

// ---------------- GEMM 2: V projection -> f16 V^T (b,h,d,n) -----------------
// Tokens stay in natural order; within each 64-token block the 8-token 16B
// chunk c8 is stored at position c8 ^ (d&7) so attn's ds_read_b128 of the
// x32 A-fragment is bank-spread (same structure as the K-tile read: 0 confl).
__global__ __launch_bounds__(256) void gemm_v(const __bf16* __restrict__ A,
                                              const __bf16* __restrict__ Wv,
                                              const float* __restrict__ bv,
                                              _Float16* __restrict__ Vt) {
  const int tn = blockIdx.x & 7;
  const int tm = blockIdx.x >> 3;
  GEMM_CORE(A, Wv, Ec)

  const int h = nb0 >> 6;
#pragma unroll
  for (int i = 0; i < 4; ++i) {
    const int m = m0 + i * 16 + quad * 4;
    const int b = m / Nc;
    const int ntok = m - b * Nc;
    const int base = (ntok >> 6) * 64 + (((ntok >> 2) & 1) << 2);
    const int c8 = (ntok >> 3) & 7;
#pragma unroll
    for (int j = 0; j < 4; ++j) {
      const int d = j * 16 + l15;
      const float bi = bv[nb0 + j * 16 + l15];
      f16x4 v;
#pragma unroll
      for (int r = 0; r < 4; ++r) v[r] = (_Float16)(acc[i][j][r] + bi);
      const int off = base + ((c8 ^ (l15 & 7)) << 3);
      *(f16x4*)(Vt + ((size_t)(b * Hc + h) * 64 + d) * Nc + off) = v;
    }
  }
}

// ---------------- GEMM 3: output projection, fp32 + bias --------------------
__global__ __launch_bounds__(256) void gemm_out(const __bf16* __restrict__ A,
                                                const __bf16* __restrict__ Wo,
                                                const float* __restrict__ bo,
                                                float* __restrict__ C) {
  const int tn = blockIdx.x & 7;
  const int tm = blockIdx.x >> 3;
  GEMM_CORE(A, Wo, Ec)

#pragma unroll
  for (int j = 0; j < 4; ++j) {
    const int n = nb0 + j * 16 + l15;
    const float bi = bo[n];
#pragma unroll
    for (int i = 0; i < 4; ++i) {
      const int m = m0 + i * 16 + quad * 4;
#pragma unroll
      for (int r = 0; r < 4; ++r) C[(size_t)(m + r) * Ec + n] = acc[i][j][r] + bi;
    }
  }
}

// --------------------------- flash attention (R6) ---------------------------
constexpr int TQ = 128, TK = 64, NT = Nc / TK;  // 18 q-tiles, 36 k-tiles

__global__ __launch_bounds__(256) void attn(const __bf16* __restrict__ Qh,
                                            const __bf16* __restrict__ Kg,
                                            const _Float16* __restrict__ Vg,
                                            __bf16* __restrict__ Om) {
  const int bh = blockIdx.x;
  const int t = threadIdx.x, wave = t >> 6, lane = t & 63;
  const int quad = lane >> 4, l15 = lane & 15;

  __shared__ __align__(16) __bf16 Kls[3][TK * 64];
  __shared__ __align__(16) _Float16 Vls[3][TK * 64];

  const int qbase = blockIdx.y * TQ + wave * 32;
  bf16x8 bq[2][2];
#pragma unroll
  for (int s = 0; s < 2; ++s)
#pragma unroll
    for (int ks = 0; ks < 2; ++ks)
      bq[s][ks] = *(const bf16x8*)(Qh + ((size_t)bh * Nc + qbase + s * 16 + l15) * 64 +
                                   ks * 32 + quad * 8);
  // Pin the Q-fragment waits HERE (before the pipeline) so the waitcnt pass
  // cannot inject a vmcnt drain inside the main loop; then zero the counter
  // baseline for the manual vmcnt bookkeeping below.
#pragma unroll
  for (int s = 0; s < 2; ++s)
#pragma unroll
    for (int ks = 0; ks < 2; ++ks) asm volatile("" : "+v"(bq[s][ks]));
  asm volatile("s_waitcnt vmcnt(0)" ::: "memory");

  const __bf16* Kbh = Kg + (size_t)bh * Nc * 64;
  const _Float16* Vbh = Vg + (size_t)bh * 64 * Nc;

  const f32x4 zero = {0.f, 0.f, 0.f, 0.f};
  f32x4 oacc[2][4] = {{zero, zero, zero, zero}, {zero, zero, zero, zero}};
  f32x4 osum[2] = {zero, zero};
  const f16x8 fones8 = {(_Float16)1.f, (_Float16)1.f, (_Float16)1.f, (_Float16)1.f,
                        (_Float16)1.f, (_Float16)1.f, (_Float16)1.f, (_Float16)1.f};

  const int vrow = lane >> 3, vcol = (lane & 7) * 8;

#define STAGE(KT2, BUF2)                                                        \
  {                                                                             \
    _Pragma("unroll") for (int i = 0; i < 2; ++i) {                             \
      const int ch = wave * 2 + i;                                              \
      __builtin_amdgcn_global_load_lds(                                         \
          GPTR(Kbh + (size_t)(KT2) * (TK * 64) + ch * 512 + lane * 8),          \
          LPTR(&Kls[BUF2][ch * 512]), 16, 0, 0);                                \
    }                                                                           \
    _Pragma("unroll") for (int i = 0; i < 2; ++i) {                             \
      const int ch = wave * 2 + i;                                              \
      const int d = ch * 8 + vrow;                                              \
      __builtin_amdgcn_global_load_lds(                                         \
          GPTR(Vbh + (size_t)d * Nc + (size_t)(KT2) * 64 + vcol),               \
          LPTR(&Vls[BUF2][ch * 512]), 16, 0, 0);                                \
    }                                                                           \
  }

  // sacc C-layout: col = q (lane&15), row = K-tile position quad*4+r.
  // With the write-side token permutation, lane quad's sacc regs
  // {[2*c2][0..3],[2*c2+1][0..3]} are exactly tokens c2*32 + quad*8 + (0..7)
  // = the k-slots of the 16x16x32_f16 B-fragment. No cross-lane traffic.
#define COMPUTE(BUF)                                                            \
  {                                                                             \
    f32x4 sacc[2][4] = {{zero, zero, zero, zero}, {zero, zero, zero, zero}};    \
    __builtin_amdgcn_s_setprio(1);                                              \
    _Pragma("unroll") for (int ks = 0; ks < 2; ++ks) {                          \
      _Pragma("unroll") for (int ct = 0; ct < 4; ++ct) {                        \
        const bf16x8 ak = *(const bf16x8*)(&Kls[BUF][(ct * 16 + l15) * 64 +     \
            (((ks * 4 + quad) ^ (l15 & 7)) << 3)]);                             \
        sacc[0][ct] = mfma16(ak, bq[0][ks], sacc[0][ct]);                       \
        sacc[1][ct] = mfma16(ak, bq[1][ks], sacc[1][ct]);                       \
      }                                                                         \
    }                                                                           \
    __builtin_amdgcn_s_setprio(0);                                              \
    f16x8 pf[2][2];                                                             \
    _Pragma("unroll") for (int s = 0; s < 2; ++s)                               \
      _Pragma("unroll") for (int c2 = 0; c2 < 2; ++c2) {                        \
        _Pragma("unroll") for (int r = 0; r < 4; ++r) {                         \
          pf[s][c2][r]     = (_Float16)exp2f(sacc[s][2 * c2][r]);               \
          pf[s][c2][4 + r] = (_Float16)exp2f(sacc[s][2 * c2 + 1][r]);           \
        }                                                                       \
      }                                                                         \
    __builtin_amdgcn_s_setprio(1);                                              \
    _Pragma("unroll") for (int c2 = 0; c2 < 2; ++c2) {                          \
      _Pragma("unroll") for (int dt = 0; dt < 4; ++dt) {                        \
        const f16x8 av = *(const f16x8*)(&Vls[BUF][(dt * 16 + l15) * 64 +       \
            (((c2 * 4 + quad) ^ (l15 & 7)) << 3)]);                             \
        oacc[0][dt] = mfmah32(av, pf[0][c2], oacc[0][dt]);                      \
        oacc[1][dt] = mfmah32(av, pf[1][c2], oacc[1][dt]);                      \
      }                                                                         \
      osum[0] = mfmah32(fones8, pf[0][c2], osum[0]);                            \
      osum[1] = mfmah32(fones8, pf[1][c2], osum[1]);                            \
    }                                                                           \
    __builtin_amdgcn_s_setprio(0);                                              \
  }

  // One barrier per K-tile. vmcnt(4) = 4 loads/wave of the next tile stay in
  // flight; vmcnt retires in order, so the tile needed NOW is guaranteed done.
  // Stage is AFTER the barrier: buffer (kt+2)%3 was last read in COMPUTE(kt-1)
  // which every wave finished before arriving here.
#define PHASE(KT, BUF, WN, DS)                                                  \
  asm volatile("s_waitcnt vmcnt(" #WN ")" ::: "memory");                        \
  __builtin_amdgcn_s_barrier();                                                 \
  asm volatile("" ::: "memory");                                                \
  if (DS) STAGE((KT) + 2, ((BUF) + 2) % 3)                                      \
  COMPUTE(BUF)

  STAGE(0, 0)
  STAGE(1, 1)

#pragma unroll 1
  for (int kt = 0; kt < NT - 3; kt += 3) {
    PHASE(kt, 0, 4, 1)
    PHASE(kt + 1, 1, 4, 1)
    PHASE(kt + 2, 2, 4, 1)
  }
  PHASE(NT - 3, 0, 4, 1)   // stages tile NT-1
  PHASE(NT - 2, 1, 4, 0)
  PHASE(NT - 1, 2, 0, 0)

  // ---- epilogue: rinv from ones-MFMA (all regs equal), normalize, store ----
  const int b = bh >> 4, h = bh & 15;
#pragma unroll
  for (int s = 0; s < 2; ++s) {
    const float rinv = 1.0f / osum[s][0];
    __bf16* Op = Om + ((size_t)b * Nc + qbase + s * 16 + l15) * Ec + h * 64 + quad * 4;
#pragma unroll
    for (int dt = 0; dt < 4; ++dt) {
      bf16x4 o;
#pragma unroll
      for (int r = 0; r < 4; ++r) o[r] = (__bf16)(oacc[s][dt][r] * rinv);
      *(bf16x4*)(Op + dt * 16) = o;
    }
  }
#undef STAGE
#undef COMPUTE
#undef PHASE
}

// ---------------------------------------------------------------------------
extern "C" void kernel_launch(void* const* d_in, const int* in_sizes, int n_in,
                              void* d_out, int out_size, void* d_ws, size_t ws_size,
                              hipStream_t stream) {
  const float* q  = (const float*)d_in[0];
  const float* k  = (const float*)d_in[1];
  const float* v  = (const float*)d_in[2];
  const float* Wq = (const float*)d_in[3];
  const float* bq = (const float*)d_in[4];
  const float* Wk = (const float*)d_in[5];
  const float* bk = (const float*)d_in[6];
  const float* Wv = (const float*)d_in[7];
  const float* bv = (const float*)d_in[8];
  const float* Wo = (const float*)d_in[9];
  const float* bo = (const float*)d_in[10];
  float* out = (float*)d_out;

  const size_t EE = (size_t)Ec * Ec;          // 1 M elems
  const size_t BNE = (size_t)BNc * Ec;        // 9.4 M elems

  // workspace carve (~102 MB with aliasing). qb and kb MUST be adjacent:
  // gemm_qk indexes A as qb + proj*BNE.
  char* w = (char*)d_ws;
  __bf16* Wqkb = (__bf16*)w; w += 2 * EE * 2;  // W_q rows | W_k rows (2048x1024)
  __bf16* Wvb  = (__bf16*)w; w += EE * 2;
  __bf16* Wob  = (__bf16*)w; w += EE * 2;
  __bf16* qb   = (__bf16*)w; w += BNE * 2;
  __bf16* kb   = (__bf16*)w; w += BNE * 2;    // == qb + BNE
  __bf16* vb   = (__bf16*)w; w += BNE * 2;
  __bf16* Qhp  = (__bf16*)w; w += BNE * 2;
  __bf16* Khp  = (__bf16*)w; w += BNE * 2;    // token-permuted + d-swizzled
  _Float16* Vtp = (_Float16*)kb;  // kb dead after gemm_qk; gemm_v writes here
  __bf16* Omp = qb;               // qb dead after gemm_qk; attn writes here

  const dim3 blk(256);
  const dim3 gCvtW(EE / 8 / 256);     // 512
  const dim3 gCvtA(BNE / 8 / 256);    // 4608
  const dim3 gQK(16 * (BNc / 128));   // 1152
  const dim3 gG(8 * (BNc / 128));     // 576
  const dim3 gAttn(Bc * Hc, Nc / TQ);

  cvt_bf16<<<gCvtW, blk, 0, stream>>>(Wq, Wqkb, (int)EE);
  cvt_bf16<<<gCvtW, blk, 0, stream>>>(Wk, Wqkb + EE, (int)EE);
  cvt_bf16<<<gCvtW, blk, 0, stream>>>(Wv, Wvb, (int)EE);
  cvt_bf16<<<gCvtW, blk, 0, stream>>>(Wo, Wob, (int)EE);
  cvt_bf16<<<gCvtA, blk, 0, stream>>>(q, qb, (int)BNE);
  cvt_bf16<<<gCvtA, blk, 0, stream>>>(k, kb, (int)BNE);
  cvt_bf16<<<gCvtA, blk, 0, stream>>>(v, vb, (int)BNE);

  const float qscale = 0.125f * 1.44269504088896340736f;  // 1/sqrt(64) * log2(e)

  gemm_qk<<<gQK, blk, 0, stream>>>(qb, Wqkb, bq, bk, Qhp, Khp, qscale);
  gemm_v<<<gG, blk, 0, stream>>>(vb, Wvb, bv, Vtp);
  attn<<<gAttn, blk, 0, stream>>>(Qhp, Khp, Vtp, Omp);
  gemm_out<<<gG, blk, 0, stream>>>(Omp, Wob, bo, out);
}

// Round 3
// 490.325 us; speedup vs baseline: 1.0539x; 1.0539x over previous
//
#include <hip/hip_runtime.h>
#include <cstdint>
#include <cstddef>

// ---------------------------------------------------------------------------
// CrossAttention2D: out = softmax((rope(XqWq^T) rope(XkWk^T)^T)/8) (XvWv^T) Wo^T
// B=4, N=48*48=2304, E=1024, H=16, D=64. bf16 MFMA, fp32 accum.
// R8 (= R7 with the cvt_pkrtz type fixed): GEMM_CORE is the R5 single-buffer
//     2-barrier structure (R6's 3-buffer GEMM cost +48us via LDS 16->48KB
//     occupancy drop). attn keeps the R6 full-rate 16x16x32_f16 PV +
//     3-buffer counted-vmcnt pipeline and gains packed P->f16 conversion
//     via v_cvt_pkrtz_f16_f32 (builtin returns __fp16x2; bridged through a
//     union to the _Float16x8 MFMA operand).
// ---------------------------------------------------------------------------

typedef __bf16 bf16x8 __attribute__((ext_vector_type(8)));
typedef __bf16 bf16x4 __attribute__((ext_vector_type(4)));
typedef __fp16 fp16v2 __attribute__((ext_vector_type(2)));
typedef _Float16 f16x4 __attribute__((ext_vector_type(4)));
typedef _Float16 f16x8 __attribute__((ext_vector_type(8)));
typedef float f32x4 __attribute__((ext_vector_type(4)));

constexpr int Bc = 4, Hc = 16, Nc = 2304, Ec = 1024, WPc = 48;
constexpr int BNc = Bc * Nc;  // 9216

__device__ __forceinline__ f32x4 mfma16(bf16x8 a, bf16x8 b, f32x4 c) {
  return __builtin_amdgcn_mfma_f32_16x16x32_bf16(a, b, c, 0, 0, 0);
}
__device__ __forceinline__ f32x4 mfmah32(f16x8 a, f16x8 b, f32x4 c) {
  return __builtin_amdgcn_mfma_f32_16x16x32_f16(a, b, c, 0, 0, 0);
}

#define GPTR(p) ((const __attribute__((address_space(1))) void*)(p))
#define LPTR(p) ((__attribute__((address_space(3))) void*)(p))

// --------------------------- fp32 -> bf16 convert ---------------------------
__global__ __launch_bounds__(256) void cvt_bf16(const float* __restrict__ s,
                                                __bf16* __restrict__ d, int n) {
  int i = (blockIdx.x * 256 + threadIdx.x) * 8;
  if (i >= n) return;
  float4 f0 = *(const float4*)(s + i);
  float4 f1 = *(const float4*)(s + i + 4);
  bf16x8 v;
  v[0] = (__bf16)f0.x; v[1] = (__bf16)f0.y; v[2] = (__bf16)f0.z; v[3] = (__bf16)f0.w;
  v[4] = (__bf16)f1.x; v[5] = (__bf16)f1.y; v[6] = (__bf16)f1.z; v[7] = (__bf16)f1.w;
  *(bf16x8*)(d + i) = v;
}

// ---------------- shared GEMM core: 128x128 tile, BK=32, 4 waves ------------
// R5 structure: single LDS buffer, global_load_lds staging, 2 barriers/K-step.
#define GEMM_CORE(APTR, WPTR, KDIM)                                             \
  __shared__ __align__(16) __bf16 As[128 * 32];                                 \
  __shared__ __align__(16) __bf16 Bs[128 * 32];                                 \
  const int t = threadIdx.x;                                                    \
  const int lane = t & 63, wave = t >> 6;                                       \
  const int wm = wave & 1, wn = wave >> 1;                                      \
  const int quad = lane >> 4, l15 = lane & 15;                                  \
  const int rowInC = lane >> 2, colC = (lane & 3) * 8;                          \
  const __bf16* Ab = (APTR) + (size_t)(tm * 128) * (KDIM);                      \
  const __bf16* Wb = (WPTR) + (size_t)(tn * 128) * (KDIM);                      \
  f32x4 zero = {0.f, 0.f, 0.f, 0.f};                                            \
  f32x4 acc[4][4];                                                              \
  for (int i = 0; i < 4; ++i)                                                   \
    for (int j = 0; j < 4; ++j) acc[i][j] = zero;                               \
  for (int kk = 0; kk < (KDIM); kk += 32) {                                     \
    _Pragma("unroll") for (int tch = 0; tch < 2; ++tch) {                       \
      const int ch = wave * 2 + tch;                                            \
      const int row = ch * 16 + rowInC;                                         \
      __builtin_amdgcn_global_load_lds(GPTR(Ab + (size_t)row * (KDIM) + kk + colC), \
                                       LPTR(As + ch * 512), 16, 0, 0);          \
      __builtin_amdgcn_global_load_lds(GPTR(Wb + (size_t)row * (KDIM) + kk + colC), \
                                       LPTR(Bs + ch * 512), 16, 0, 0);          \
    }                                                                           \
    __syncthreads();                                                            \
    bf16x8 af[4], bfg[4];                                                       \
    _Pragma("unroll") for (int i = 0; i < 4; ++i)                               \
        af[i] = *(const bf16x8*)(As + (wm * 64 + i * 16 + l15) * 32 + quad * 8);\
    _Pragma("unroll") for (int j = 0; j < 4; ++j)                               \
        bfg[j] = *(const bf16x8*)(Bs + (wn * 64 + j * 16 + l15) * 32 + quad * 8);\
    _Pragma("unroll") for (int i = 0; i < 4; ++i)                               \
      _Pragma("unroll") for (int j = 0; j < 4; ++j)                             \
        acc[i][j] = mfma16(af[i], bfg[j], acc[i][j]);                           \
    __syncthreads();                                                            \
  }                                                                             \
  const int m0 = tm * 128 + wm * 64;                                            \
  const int nb0 = tn * 128 + wn * 64;

// ---------------- GEMM 1: fused Q+K projection + RoPE + head pack -----------
// Col tiles 0..7 -> Q (natural order); 8..15 -> K. K rows get BOTH the 16B
// d-chunk XOR swizzle (by stored-position low bits) AND the token
// bit-permutation within each 64-block: t64=[hi q1 q0 c r1 r0] is stored at
// position p=[hi c q1 q0 r1 r0], so QK^T's C-regs line up with the k-slots
// (k = quad*8+j) of the 16x16x32 PV B-fragment with zero cross-lane traffic.
__global__ __launch_bounds__(256) void gemm_qk(const __bf16* __restrict__ qkb,
                                               const __bf16* __restrict__ Wqk,
                                               const float* __restrict__ bq,
                                               const float* __restrict__ bk,
                                               __bf16* __restrict__ Qhp,
                                               __bf16* __restrict__ Khp,
                                               float qscale) {
  const int tn = blockIdx.x & 15;   // 16 col tiles over 2048
  const int tm = blockIdx.x >> 4;   // 72 row tiles
  const int proj = tn >> 3;         // 0 = Q, 1 = K (block-uniform)
  const __bf16* Asel = qkb + (size_t)proj * BNc * Ec;
  GEMM_CORE(Asel, Wqk, Ec)

  const int h = (nb0 >> 6) & 15;
  const float scale = proj ? 1.0f : qscale;
  __bf16* O = proj ? Khp : Qhp;
  const float* bb = proj ? bk : bq;
  float bj[4];
#pragma unroll
  for (int j = 0; j < 4; ++j) bj[j] = bb[(nb0 + j * 16 + l15) & 1023];
  const float f = exp2f(-(float)l15 * 0.8304820237218406f);
  const int lo3 = l15 & 7, hi8 = l15 >> 3;
#pragma unroll
  for (int i = 0; i < 4; ++i) {
#pragma unroll
    for (int r = 0; r < 4; ++r) {
      const int m = m0 + i * 16 + quad * 4 + r;
      const int b = m / Nc;
      const int ntok = m - b * Nc;
      const int ph = ntok / WPc, pw = ntok - (ntok / WPc) * WPc;
      float sh, ch, sw, cw;
      __sincosf((float)ph * f, &sh, &ch);
      __sincosf((float)pw * f, &sw, &cw);
      const float x0 = acc[i][0][r] + bj[0];
      const float x1 = acc[i][1][r] + bj[1];
      const float x2 = acc[i][2][r] + bj[2];
      const float x3 = acc[i][3][r] + bj[3];
      int wtok = ntok;
      if (proj) {
        const int t64 = ntok & 63;
        wtok = (ntok & ~63) | (t64 & 35) | ((t64 & 4) << 2) | ((t64 & 24) >> 1);
      }
      __bf16* Op = O + ((size_t)(b * Hc + h) * Nc + wtok) * 64;
      const int n7 = proj ? (wtok & 7) : 0;
      Op[(((0 + hi8) ^ n7) << 3) | lo3] = (__bf16)((x0 * ch - x1 * sh) * scale);
      Op[(((2 + hi8) ^ n7) << 3) | lo3] = (__bf16)((x1 * ch + x0 * sh) * scale);
      Op[(((4 + hi8) ^ n7) << 3) | lo3] = (__bf16)((x2 * cw - x3 * sw) * scale);
      Op[(((6 + hi8) ^ n7) << 3) | lo3] = (__bf16)((x3 * cw + x2 * sw) * scale);
    }
  }
}

// ---------------- GEMM 2: V projection -> f16 V^T (b,h,d,n) -----------------
// Tokens stay in natural order; within each 64-token block the 8-token 16B
// chunk c8 is stored at position c8 ^ (d&7) so attn's ds_read_b128 of the
// x32 A-fragment is bank-spread (same structure as the K-tile read: 0 confl).
__global__ __launch_bounds__(256) void gemm_v(const __bf16* __restrict__ A,
                                              const __bf16* __restrict__ Wv,
                                              const float* __restrict__ bv,
                                              _Float16* __restrict__ Vt) {
  const int tn = blockIdx.x & 7;
  const int tm = blockIdx.x >> 3;
  GEMM_CORE(A, Wv, Ec)

  const int h = nb0 >> 6;
#pragma unroll
  for (int i = 0; i < 4; ++i) {
    const int m = m0 + i * 16 + quad * 4;
    const int b = m / Nc;
    const int ntok = m - b * Nc;
    const int base = (ntok >> 6) * 64 + (((ntok >> 2) & 1) << 2);
    const int c8 = (ntok >> 3) & 7;
#pragma unroll
    for (int j = 0; j < 4; ++j) {
      const int d = j * 16 + l15;
      const float bi = bv[nb0 + j * 16 + l15];
      f16x4 v;
#pragma unroll
      for (int r = 0; r < 4; ++r) v[r] = (_Float16)(acc[i][j][r] + bi);
      const int off = base + ((c8 ^ (l15 & 7)) << 3);
      *(f16x4*)(Vt + ((size_t)(b * Hc + h) * 64 + d) * Nc + off) = v;
    }
  }
}

// ---------------- GEMM 3: output projection, fp32 + bias --------------------
__global__ __launch_bounds__(256) void gemm_out(const __bf16* __restrict__ A,
                                                const __bf16* __restrict__ Wo,
                                                const float* __restrict__ bo,
                                                float* __restrict__ C) {
  const int tn = blockIdx.x & 7;
  const int tm = blockIdx.x >> 3;
  GEMM_CORE(A, Wo, Ec)

#pragma unroll
  for (int j = 0; j < 4; ++j) {
    const int n = nb0 + j * 16 + l15;
    const float bi = bo[n];
#pragma unroll
    for (int i = 0; i < 4; ++i) {
      const int m = m0 + i * 16 + quad * 4;
#pragma unroll
      for (int r = 0; r < 4; ++r) C[(size_t)(m + r) * Ec + n] = acc[i][j][r] + bi;
    }
  }
}

// --------------------------- flash attention (R8) ---------------------------
constexpr int TQ = 128, TK = 64, NT = Nc / TK;  // 18 q-tiles, 36 k-tiles

__global__ __launch_bounds__(256) void attn(const __bf16* __restrict__ Qh,
                                            const __bf16* __restrict__ Kg,
                                            const _Float16* __restrict__ Vg,
                                            __bf16* __restrict__ Om) {
  const int bh = blockIdx.x;
  const int t = threadIdx.x, wave = t >> 6, lane = t & 63;
  const int quad = lane >> 4, l15 = lane & 15;

  __shared__ __align__(16) __bf16 Kls[3][TK * 64];
  __shared__ __align__(16) _Float16 Vls[3][TK * 64];

  const int qbase = blockIdx.y * TQ + wave * 32;
  bf16x8 bq[2][2];
#pragma unroll
  for (int s = 0; s < 2; ++s)
#pragma unroll
    for (int ks = 0; ks < 2; ++ks)
      bq[s][ks] = *(const bf16x8*)(Qh + ((size_t)bh * Nc + qbase + s * 16 + l15) * 64 +
                                   ks * 32 + quad * 8);
  // Pin the Q-fragment waits HERE (before the pipeline) so the waitcnt pass
  // cannot inject a vmcnt drain inside the main loop; then zero the counter
  // baseline for the manual vmcnt bookkeeping below.
#pragma unroll
  for (int s = 0; s < 2; ++s)
#pragma unroll
    for (int ks = 0; ks < 2; ++ks) asm volatile("" : "+v"(bq[s][ks]));
  asm volatile("s_waitcnt vmcnt(0)" ::: "memory");

  const __bf16* Kbh = Kg + (size_t)bh * Nc * 64;
  const _Float16* Vbh = Vg + (size_t)bh * 64 * Nc;

  const f32x4 zero = {0.f, 0.f, 0.f, 0.f};
  f32x4 oacc[2][4] = {{zero, zero, zero, zero}, {zero, zero, zero, zero}};
  f32x4 osum[2] = {zero, zero};
  const f16x8 fones8 = {(_Float16)1.f, (_Float16)1.f, (_Float16)1.f, (_Float16)1.f,
                        (_Float16)1.f, (_Float16)1.f, (_Float16)1.f, (_Float16)1.f};

  const int vrow = lane >> 3, vcol = (lane & 7) * 8;

#define STAGE(KT2, BUF2)                                                        \
  {                                                                             \
    _Pragma("unroll") for (int i = 0; i < 2; ++i) {                             \
      const int ch = wave * 2 + i;                                              \
      __builtin_amdgcn_global_load_lds(                                         \
          GPTR(Kbh + (size_t)(KT2) * (TK * 64) + ch * 512 + lane * 8),          \
          LPTR(&Kls[BUF2][ch * 512]), 16, 0, 0);                                \
    }                                                                           \
    _Pragma("unroll") for (int i = 0; i < 2; ++i) {                             \
      const int ch = wave * 2 + i;                                              \
      const int d = ch * 8 + vrow;                                              \
      __builtin_amdgcn_global_load_lds(                                         \
          GPTR(Vbh + (size_t)d * Nc + (size_t)(KT2) * 64 + vcol),               \
          LPTR(&Vls[BUF2][ch * 512]), 16, 0, 0);                                \
    }                                                                           \
  }

  // sacc C-layout: col = q (lane&15), row = K-tile position quad*4+r.
  // With the write-side token permutation, lane quad's sacc regs
  // {[2*c2][0..3],[2*c2+1][0..3]} are exactly tokens c2*32 + quad*8 + (0..7)
  // = the k-slots of the 16x16x32_f16 B-fragment. No cross-lane traffic.
  // P->f16 via cvt_pkrtz: 16 packed converts/tile instead of 32 cvt + packs.
  // osum uses the same rounded pf, so normalization is self-consistent.
#define COMPUTE(BUF)                                                            \
  {                                                                             \
    f32x4 sacc[2][4] = {{zero, zero, zero, zero}, {zero, zero, zero, zero}};    \
    __builtin_amdgcn_s_setprio(1);                                              \
    _Pragma("unroll") for (int ks = 0; ks < 2; ++ks) {                          \
      _Pragma("unroll") for (int ct = 0; ct < 4; ++ct) {                        \
        const bf16x8 ak = *(const bf16x8*)(&Kls[BUF][(ct * 16 + l15) * 64 +     \
            (((ks * 4 + quad) ^ (l15 & 7)) << 3)]);                             \
        sacc[0][ct] = mfma16(ak, bq[0][ks], sacc[0][ct]);                       \
        sacc[1][ct] = mfma16(ak, bq[1][ks], sacc[1][ct]);                       \
      }                                                                         \
    }                                                                           \
    __builtin_amdgcn_s_setprio(0);                                              \
    f16x8 pf[2][2];                                                             \
    _Pragma("unroll") for (int s = 0; s < 2; ++s)                               \
      _Pragma("unroll") for (int c2 = 0; c2 < 2; ++c2) {                        \
        union { fp16v2 h2[4]; f16x8 h8; } u;                                    \
        u.h2[0] = __builtin_amdgcn_cvt_pkrtz(exp2f(sacc[s][2 * c2][0]),         \
                                             exp2f(sacc[s][2 * c2][1]));        \
        u.h2[1] = __builtin_amdgcn_cvt_pkrtz(exp2f(sacc[s][2 * c2][2]),         \
                                             exp2f(sacc[s][2 * c2][3]));        \
        u.h2[2] = __builtin_amdgcn_cvt_pkrtz(exp2f(sacc[s][2 * c2 + 1][0]),     \
                                             exp2f(sacc[s][2 * c2 + 1][1]));    \
        u.h2[3] = __builtin_amdgcn_cvt_pkrtz(exp2f(sacc[s][2 * c2 + 1][2]),     \
                                             exp2f(sacc[s][2 * c2 + 1][3]));    \
        pf[s][c2] = u.h8;                                                       \
      }                                                                         \
    __builtin_amdgcn_s_setprio(1);                                              \
    _Pragma("unroll") for (int c2 = 0; c2 < 2; ++c2) {                          \
      _Pragma("unroll") for (int dt = 0; dt < 4; ++dt) {                        \
        const f16x8 av = *(const f16x8*)(&Vls[BUF][(dt * 16 + l15) * 64 +       \
            (((c2 * 4 + quad) ^ (l15 & 7)) << 3)]);                             \
        oacc[0][dt] = mfmah32(av, pf[0][c2], oacc[0][dt]);                      \
        oacc[1][dt] = mfmah32(av, pf[1][c2], oacc[1][dt]);                      \
      }                                                                         \
      osum[0] = mfmah32(fones8, pf[0][c2], osum[0]);                            \
      osum[1] = mfmah32(fones8, pf[1][c2], osum[1]);                            \
    }                                                                           \
    __builtin_amdgcn_s_setprio(0);                                              \
  }

  // One barrier per K-tile. vmcnt(4) = 4 loads/wave of the next tile stay in
  // flight; vmcnt retires in order, so the tile needed NOW is guaranteed done.
  // Stage is AFTER the barrier: buffer (kt+2)%3 was last read in COMPUTE(kt-1)
  // which every wave finished before arriving here.
#define PHASE(KT, BUF, WN, DS)                                                  \
  asm volatile("s_waitcnt vmcnt(" #WN ")" ::: "memory");                        \
  __builtin_amdgcn_s_barrier();                                                 \
  asm volatile("" ::: "memory");                                                \
  if (DS) STAGE((KT) + 2, ((BUF) + 2) % 3)                                      \
  COMPUTE(BUF)

  STAGE(0, 0)
  STAGE(1, 1)

#pragma unroll 1
  for (int kt = 0; kt < NT - 3; kt += 3) {
    PHASE(kt, 0, 4, 1)
    PHASE(kt + 1, 1, 4, 1)
    PHASE(kt + 2, 2, 4, 1)
  }
  PHASE(NT - 3, 0, 4, 1)   // stages tile NT-1
  PHASE(NT - 2, 1, 4, 0)
  PHASE(NT - 1, 2, 0, 0)

  // ---- epilogue: rinv from ones-MFMA (all regs equal), normalize, store ----
  const int b = bh >> 4, h = bh & 15;
#pragma unroll
  for (int s = 0; s < 2; ++s) {
    const float rinv = 1.0f / osum[s][0];
    __bf16* Op = Om + ((size_t)b * Nc + qbase + s * 16 + l15) * Ec + h * 64 + quad * 4;
#pragma unroll
    for (int dt = 0; dt < 4; ++dt) {
      bf16x4 o;
#pragma unroll
      for (int r = 0; r < 4; ++r) o[r] = (__bf16)(oacc[s][dt][r] * rinv);
      *(bf16x4*)(Op + dt * 16) = o;
    }
  }
#undef STAGE
#undef COMPUTE
#undef PHASE
}

// ---------------------------------------------------------------------------
extern "C" void kernel_launch(void* const* d_in, const int* in_sizes, int n_in,
                              void* d_out, int out_size, void* d_ws, size_t ws_size,
                              hipStream_t stream) {
  const float* q  = (const float*)d_in[0];
  const float* k  = (const float*)d_in[1];
  const float* v  = (const float*)d_in[2];
  const float* Wq = (const float*)d_in[3];
  const float* bq = (const float*)d_in[4];
  const float* Wk = (const float*)d_in[5];
  const float* bk = (const float*)d_in[6];
  const float* Wv = (const float*)d_in[7];
  const float* bv = (const float*)d_in[8];
  const float* Wo = (const float*)d_in[9];
  const float* bo = (const float*)d_in[10];
  float* out = (float*)d_out;

  const size_t EE = (size_t)Ec * Ec;          // 1 M elems
  const size_t BNE = (size_t)BNc * Ec;        // 9.4 M elems

  // workspace carve (~102 MB with aliasing). qb and kb MUST be adjacent:
  // gemm_qk indexes A as qb + proj*BNE.
  char* w = (char*)d_ws;
  __bf16* Wqkb = (__bf16*)w; w += 2 * EE * 2;  // W_q rows | W_k rows (2048x1024)
  __bf16* Wvb  = (__bf16*)w; w += EE * 2;
  __bf16* Wob  = (__bf16*)w; w += EE * 2;
  __bf16* qb   = (__bf16*)w; w += BNE * 2;
  __bf16* kb   = (__bf16*)w; w += BNE * 2;    // == qb + BNE
  __bf16* vb   = (__bf16*)w; w += BNE * 2;
  __bf16* Qhp  = (__bf16*)w; w += BNE * 2;
  __bf16* Khp  = (__bf16*)w; w += BNE * 2;    // token-permuted + d-swizzled
  _Float16* Vtp = (_Float16*)kb;  // kb dead after gemm_qk; gemm_v writes here
  __bf16* Omp = qb;               // qb dead after gemm_qk; attn writes here

  const dim3 blk(256);
  const dim3 gCvtW(EE / 8 / 256);     // 512
  const dim3 gCvtA(BNE / 8 / 256);    // 4608
  const dim3 gQK(16 * (BNc / 128));   // 1152
  const dim3 gG(8 * (BNc / 128));     // 576
  const dim3 gAttn(Bc * Hc, Nc / TQ);

  cvt_bf16<<<gCvtW, blk, 0, stream>>>(Wq, Wqkb, (int)EE);
  cvt_bf16<<<gCvtW, blk, 0, stream>>>(Wk, Wqkb + EE, (int)EE);
  cvt_bf16<<<gCvtW, blk, 0, stream>>>(Wv, Wvb, (int)EE);
  cvt_bf16<<<gCvtW, blk, 0, stream>>>(Wo, Wob, (int)EE);
  cvt_bf16<<<gCvtA, blk, 0, stream>>>(q, qb, (int)BNE);
  cvt_bf16<<<gCvtA, blk, 0, stream>>>(k, kb, (int)BNE);
  cvt_bf16<<<gCvtA, blk, 0, stream>>>(v, vb, (int)BNE);

  const float qscale = 0.125f * 1.44269504088896340736f;  // 1/sqrt(64) * log2(e)

  gemm_qk<<<gQK, blk, 0, stream>>>(qb, Wqkb, bq, bk, Qhp, Khp, qscale);
  gemm_v<<<gG, blk, 0, stream>>>(vb, Wvb, bv, Vtp);
  attn<<<gAttn, blk, 0, stream>>>(Qhp, Khp, Vtp, Omp);
  gemm_out<<<gG, blk, 0, stream>>>(Omp, Wob, bo, out);
}